// Round 5
// baseline (1974.050 us; speedup 1.0000x reference)
//
#include <hip/hip_runtime.h>
#include <hip/hip_bf16.h>

typedef _Float16 f16;
typedef f16   f16x8 __attribute__((ext_vector_type(8)));
typedef f16   f16x4 __attribute__((ext_vector_type(4)));
typedef float f32x4 __attribute__((ext_vector_type(4)));

#define HW 36864      /* 192*192 */
#define TS 9437184    /* 256*36864 : per-plane per-batch elements */

// ---------------------------------------------------------------------------
// Pre-kernel: W (fp32 256x256) -> 5 fp16 planes: Wq_hi, Wq_lo, Wk_hi, Wk_lo, Wv
// ---------------------------------------------------------------------------
__global__ __launch_bounds__(256) void convert_w_kernel(
    const float* __restrict__ wq, const float* __restrict__ wk,
    const float* __restrict__ wv, f16* __restrict__ wp) {
  int i = blockIdx.x * 256 + threadIdx.x;  // 0 .. 65535
  float a = wq[i], b = wk[i], c = wv[i];
  f16 ah = (f16)a, bh = (f16)b;
  wp[i]               = ah;
  wp[65536 + i]       = (f16)(a - (float)ah);
  wp[2 * 65536 + i]   = bh;
  wp[3 * 65536 + i]   = (f16)(b - (float)bh);
  wp[4 * 65536 + i]   = (f16)c;
}

// ---------------------------------------------------------------------------
// Stage 1: 1x1 conv GEMM  out[o,n] = sum_i W[o,i] x[i,n] + b[o]
// t=0 (q), t=1 (k): 3-pass hi/lo, outputs hi+lo fp16 planes. t=2 (v): 1 pass.
// grid = (576, 3), block = 256.
// ---------------------------------------------------------------------------
__global__ __launch_bounds__(256) void conv1x1_kernel(
    const float* __restrict__ xq, const float* __restrict__ xk, const float* __restrict__ xv,
    const f16* __restrict__ wp,
    const float* __restrict__ bq, const float* __restrict__ bk, const float* __restrict__ bv,
    f16* __restrict__ qkv) {
  const int t = blockIdx.y;
  const float* __restrict__ in   = (t == 0) ? xq : (t == 1 ? xk : xv);
  const float* __restrict__ bias = (t == 0) ? bq : (t == 1 ? bk : bv);
  const f16* __restrict__ Whi = wp + (2 * t) * 65536;
  const f16* __restrict__ Wlo = wp + (2 * t + 1) * 65536;
  f16* __restrict__ outhi = qkv + (size_t)(2 * t) * TS;
  f16* __restrict__ outlo = qkv + (size_t)(2 * t + 1) * TS;

  const int n0  = blockIdx.x * 64;
  const int tid = threadIdx.x;
  const int l   = tid & 63;
  const int wv  = tid >> 6;
  const int lr  = l & 15, lg = l >> 4;

  __shared__ f16 Xhi[64][264];
  __shared__ f16 Xlo[64][264];

#pragma unroll
  for (int it = 0; it < 8; ++it) {
    const int ib = it * 32 + wv * 8;
    float v[8];
#pragma unroll
    for (int j = 0; j < 8; ++j) v[j] = in[(size_t)(ib + j) * HW + n0 + l];
    union { f16 h[8]; f16x8 vec; } uh, ul;
#pragma unroll
    for (int j = 0; j < 8; ++j) {
      f16 h = (f16)v[j];
      uh.h[j] = h;
      ul.h[j] = (f16)(v[j] - (float)h);
    }
    *(f16x8*)&Xhi[l][ib] = uh.vec;
    *(f16x8*)&Xlo[l][ib] = ul.vec;
  }
  __syncthreads();

  f32x4 acc[4][4];
#pragma unroll
  for (int fo = 0; fo < 4; ++fo)
#pragma unroll
    for (int fn = 0; fn < 4; ++fn) acc[fo][fn] = (f32x4){0.f, 0.f, 0.f, 0.f};

  const int obase = wv * 64;
#pragma unroll
  for (int ks = 0; ks < 8; ++ks) {
    f16x8 awh[4], bxh[4];
#pragma unroll
    for (int fo = 0; fo < 4; ++fo)
      awh[fo] = *(const f16x8*)(Whi + (obase + fo * 16 + lr) * 256 + ks * 32 + lg * 8);
#pragma unroll
    for (int fn = 0; fn < 4; ++fn)
      bxh[fn] = *(const f16x8*)&Xhi[lr + 16 * fn][ks * 32 + lg * 8];
#pragma unroll
    for (int fo = 0; fo < 4; ++fo)
#pragma unroll
      for (int fn = 0; fn < 4; ++fn)
        acc[fo][fn] = __builtin_amdgcn_mfma_f32_16x16x32_f16(awh[fo], bxh[fn], acc[fo][fn], 0, 0, 0);
    if (t < 2) {
      f16x8 awl[4], bxl[4];
#pragma unroll
      for (int fo = 0; fo < 4; ++fo)
        awl[fo] = *(const f16x8*)(Wlo + (obase + fo * 16 + lr) * 256 + ks * 32 + lg * 8);
#pragma unroll
      for (int fn = 0; fn < 4; ++fn)
        bxl[fn] = *(const f16x8*)&Xlo[lr + 16 * fn][ks * 32 + lg * 8];
#pragma unroll
      for (int fo = 0; fo < 4; ++fo)
#pragma unroll
        for (int fn = 0; fn < 4; ++fn) {
          acc[fo][fn] = __builtin_amdgcn_mfma_f32_16x16x32_f16(awl[fo], bxh[fn], acc[fo][fn], 0, 0, 0);
          acc[fo][fn] = __builtin_amdgcn_mfma_f32_16x16x32_f16(awh[fo], bxl[fn], acc[fo][fn], 0, 0, 0);
        }
    }
  }

#pragma unroll
  for (int fo = 0; fo < 4; ++fo) {
    const int orow = obase + fo * 16 + lg * 4;
    float bz[4];
#pragma unroll
    for (int r = 0; r < 4; ++r) bz[r] = bias[orow + r];
#pragma unroll
    for (int fn = 0; fn < 4; ++fn)
#pragma unroll
      for (int r = 0; r < 4; ++r) {
        float val = acc[fo][fn][r] + bz[r];
        size_t idx = (size_t)(orow + r) * HW + n0 + 16 * fn + lr;
        f16 h = (f16)val;
        outhi[idx] = h;
        if (t < 2) outlo[idx] = (f16)(val - (float)h);
      }
  }
}

// ---------------------------------------------------------------------------
// Stage 2: per-(b,c) attention, two-phase, 512 threads (8 waves, 2/SIMD).
// __launch_bounds__(512, 2): 8-wave block requires 2 waves/EU resident ->
// VGPR budget 256/wave. (R4's (512,1) let the allocator target 128 and spill
// the cross-phase P state to scratch: +275MB HBM traffic, 2.3x regression.)
// Phase 1: K_hi (KA) + K_lo (KB) in LDS; 3-pass QK^T; softmax; P in regs.
// Phase 2: V^T staged into KA; PV with per-(tile,ks) P round-trip via Pl
//          (aliases KB; K_lo dead after phase 1).
// Tiles: 12 tiles of 16 q-rows; wave w does tile w, waves 0-3 also tile 8+w.
// ---------------------------------------------------------------------------
__global__ __launch_bounds__(512, 2) void attn_kernel(
    const f16* __restrict__ qkv, float* __restrict__ outb) {
  const int c   = blockIdx.x;
  const int tid = threadIdx.x;
  const int l   = tid & 63;
  const int wv  = tid >> 6;          // 0..7
  const int lr  = l & 15, lg = l >> 4;

  const f16* __restrict__ qh  = qkv + (size_t)c * HW;
  const f16* __restrict__ ql  = qkv + (size_t)TS + (size_t)c * HW;
  const f16* __restrict__ kh  = qkv + 2 * (size_t)TS + (size_t)c * HW;
  const f16* __restrict__ kl_ = qkv + 3 * (size_t)TS + (size_t)c * HW;
  const f16* __restrict__ vv  = qkv + 4 * (size_t)TS + (size_t)c * HW;
  float* __restrict__ outc = outb + (size_t)c * HW;

  __shared__ f16 KA[192][200];   // phase1: K_hi   phase2: V^T
  __shared__ f16 KB[192][200];   // phase1: K_lo   phase2: Pl alias
  f16 (*Pl)[16][40] = (f16 (*)[16][40])KB;   // 8*16*40*2 = 10.2KB within KB

  // ---- phase 1 staging: K_hi -> KA, K_lo -> KB (16B chunks, coalesced)
#pragma unroll
  for (int jj = 0; jj < 9; ++jj) {
    int id = tid + jj * 512;  // 4608 chunks per plane
    int g = id / 24, wo = id % 24;
    *(f16x8*)&KA[g][wo * 8] = *(const f16x8*)(kh + g * 192 + wo * 8);
    *(f16x8*)&KB[g][wo * 8] = *(const f16x8*)(kl_ + g * 192 + wo * 8);
  }
  __syncthreads();

  float rs[2][4];
  f16x4 pv[2][12];      // packed unnormalized P for up to 2 tiles (48 VGPRs)

#pragma unroll
  for (int rr = 0; rr < 2; ++rr) {
    if (rr == 0 || wv < 4) {
      const int h0 = (rr * 8 + wv) * 16;

      f16x8 aqh[6], aql[6];
#pragma unroll
      for (int ks = 0; ks < 6; ++ks) {
        aqh[ks] = *(const f16x8*)(qh + (h0 + lr) * 192 + ks * 32 + lg * 8);
        aql[ks] = *(const f16x8*)(ql + (h0 + lr) * 192 + ks * 32 + lg * 8);
      }

      f32x4 S[12];
#pragma unroll
      for (int fg = 0; fg < 12; ++fg) S[fg] = (f32x4){0.f, 0.f, 0.f, 0.f};
#pragma unroll
      for (int ks = 0; ks < 6; ++ks)
#pragma unroll
        for (int fg = 0; fg < 12; ++fg) {
          f16x8 bh = *(const f16x8*)&KA[16 * fg + lr][ks * 32 + lg * 8];
          f16x8 bl = *(const f16x8*)&KB[16 * fg + lr][ks * 32 + lg * 8];
          S[fg] = __builtin_amdgcn_mfma_f32_16x16x32_f16(aqh[ks], bh, S[fg], 0, 0, 0);
          S[fg] = __builtin_amdgcn_mfma_f32_16x16x32_f16(aql[ks], bh, S[fg], 0, 0, 0);
          S[fg] = __builtin_amdgcn_mfma_f32_16x16x32_f16(aqh[ks], bl, S[fg], 0, 0, 0);
        }

      // exact softmax per row (row = 4*lg + r; 16 lanes lr hold g-chunks)
#pragma unroll
      for (int r = 0; r < 4; ++r) {
        float m = S[0][r];
#pragma unroll
        for (int fg = 1; fg < 12; ++fg) m = fmaxf(m, S[fg][r]);
        m = fmaxf(m, __shfl_xor(m, 1));
        m = fmaxf(m, __shfl_xor(m, 2));
        m = fmaxf(m, __shfl_xor(m, 4));
        m = fmaxf(m, __shfl_xor(m, 8));
        float s = 0.f;
#pragma unroll
        for (int fg = 0; fg < 12; ++fg) {
          float e = __expf(S[fg][r] - m);
          S[fg][r] = e;
          s += e;
        }
        s += __shfl_xor(s, 1);
        s += __shfl_xor(s, 2);
        s += __shfl_xor(s, 4);
        s += __shfl_xor(s, 8);
        rs[rr][r] = 1.f / s;
      }

#pragma unroll
      for (int fg = 0; fg < 12; ++fg)
#pragma unroll
        for (int r = 0; r < 4; ++r) pv[rr][fg][r] = (f16)S[fg][r];
    }
  }

  // ---- phase 2: stage V^T into KA (overwrites K_hi). KB becomes Pl.
  __syncthreads();
#pragma unroll
  for (int jj = 0; jj < 3; ++jj) {
    int id = tid + jj * 512;
    if (id < 1152) {
      int g0 = (id % 24) * 8, w0 = (id / 24) * 4;
      uint2 raw[8];
#pragma unroll
      for (int j = 0; j < 8; ++j) raw[j] = *(const uint2*)(vv + (g0 + j) * 192 + w0);
#pragma unroll
      for (int qd = 0; qd < 4; ++qd) {
        union { unsigned short s[8]; f16x8 vec; } u;
#pragma unroll
        for (int j = 0; j < 8; ++j) u.s[j] = ((const unsigned short*)&raw[j])[qd];
        *(f16x8*)&KA[w0 + qd][g0] = u.vec;
      }
    }
  }
  __syncthreads();

#pragma unroll
  for (int rr = 0; rr < 2; ++rr) {
    if (rr == 0 || wv < 4) {
      const int h0 = (rr * 8 + wv) * 16;
      f32x4 O[12];
#pragma unroll
      for (int fn = 0; fn < 12; ++fn) O[fn] = (f32x4){0.f, 0.f, 0.f, 0.f};

#pragma unroll
      for (int ks = 0; ks < 6; ++ks) {
#pragma unroll
        for (int e = 0; e < 2; ++e)
#pragma unroll
          for (int r = 0; r < 4; ++r)
            Pl[wv][lg * 4 + r][lr + 16 * e] = pv[rr][2 * ks + e][r];
        f16x8 pa = *(const f16x8*)&Pl[wv][lr][lg * 8];
#pragma unroll
        for (int fn = 0; fn < 12; ++fn) {
          f16x8 bv_ = *(const f16x8*)&KA[16 * fn + lr][ks * 32 + lg * 8];
          O[fn] = __builtin_amdgcn_mfma_f32_16x16x32_f16(pa, bv_, O[fn], 0, 0, 0);
        }
      }

#pragma unroll
      for (int fn = 0; fn < 12; ++fn)
#pragma unroll
        for (int r = 0; r < 4; ++r)
          outc[(size_t)(h0 + lg * 4 + r) * 192 + 16 * fn + lr] = O[fn][r] * rs[rr][r];
    }
  }
}

// ---------------------------------------------------------------------------
extern "C" void kernel_launch(void* const* d_in, const int* in_sizes, int n_in,
                              void* d_out, int out_size, void* d_ws, size_t ws_size,
                              hipStream_t stream) {
  const float* query = (const float*)d_in[0];
  const float* key_  = (const float*)d_in[1];
  const float* value = (const float*)d_in[2];
  const float* Wq    = (const float*)d_in[3];
  const float* bq    = (const float*)d_in[4];
  const float* Wk    = (const float*)d_in[5];
  const float* bk    = (const float*)d_in[6];
  const float* Wv    = (const float*)d_in[7];
  const float* bv    = (const float*)d_in[8];
  float* out = (float*)d_out;

  f16* wp  = (f16*)d_ws;                         // 5*65536 fp16 = 640 KB
  f16* qkv = (f16*)((char*)d_ws + 1048576);      // 5*TS fp16 = 94.4 MB (per-batch, reused)

  convert_w_kernel<<<256, 256, 0, stream>>>(Wq, Wk, Wv, wp);

  for (int b = 0; b < 8; ++b) {
    const size_t off = (size_t)b * TS;
    conv1x1_kernel<<<dim3(576, 3), 256, 0, stream>>>(
        query + off, key_ + off, value + off, wp, bq, bk, bv, qkv);
    attn_kernel<<<256, 512, 0, stream>>>(qkv, out + off);
  }
}

// Round 6
// 713.537 us; speedup vs baseline: 2.7666x; 2.7666x over previous
//
#include <hip/hip_runtime.h>
#include <hip/hip_bf16.h>

typedef _Float16 f16;
typedef f16   f16x8 __attribute__((ext_vector_type(8)));
typedef float f32x4 __attribute__((ext_vector_type(4)));

#define HW 36864      /* 192*192 */
#define TS 9437184    /* 256*36864 : per-plane per-batch elements */

// ---------------------------------------------------------------------------
// Pre-kernel: W (fp32 256x256) -> 3 fp16 planes: Wq, Wk, Wv
// ---------------------------------------------------------------------------
__global__ __launch_bounds__(256) void convert_w_kernel(
    const float* __restrict__ wq, const float* __restrict__ wk,
    const float* __restrict__ wv, f16* __restrict__ wp) {
  int i = blockIdx.x * 256 + threadIdx.x;  // 0 .. 65535
  wp[i]             = (f16)wq[i];
  wp[65536 + i]     = (f16)wk[i];
  wp[2 * 65536 + i] = (f16)wv[i];
}

// ---------------------------------------------------------------------------
// Stage 1: 1x1 conv GEMM  out[o,n] = sum_i W[o,i] x[i,n] + b[o]
// Single-pass fp16 (fp32 accumulate). grid = (576, 3), block = 256.
// ---------------------------------------------------------------------------
__global__ __launch_bounds__(256) void conv1x1_kernel(
    const float* __restrict__ xq, const float* __restrict__ xk, const float* __restrict__ xv,
    const f16* __restrict__ wp,
    const float* __restrict__ bq, const float* __restrict__ bk, const float* __restrict__ bv,
    f16* __restrict__ qkv) {
  const int t = blockIdx.y;
  const float* __restrict__ in   = (t == 0) ? xq : (t == 1 ? xk : xv);
  const float* __restrict__ bias = (t == 0) ? bq : (t == 1 ? bk : bv);
  const f16* __restrict__ W = wp + t * 65536;
  f16* __restrict__ outp    = qkv + (size_t)t * TS;

  const int n0  = blockIdx.x * 64;
  const int tid = threadIdx.x;
  const int l   = tid & 63;
  const int wv  = tid >> 6;
  const int lr  = l & 15, lg = l >> 4;

  __shared__ f16 Xt[64][264];   // [n][i], +8 pad

#pragma unroll
  for (int it = 0; it < 8; ++it) {
    const int ib = it * 32 + wv * 8;
    float v[8];
#pragma unroll
    for (int j = 0; j < 8; ++j) v[j] = in[(size_t)(ib + j) * HW + n0 + l];
    union { f16 h[8]; f16x8 vec; } u;
#pragma unroll
    for (int j = 0; j < 8; ++j) u.h[j] = (f16)v[j];
    *(f16x8*)&Xt[l][ib] = u.vec;
  }
  __syncthreads();

  f32x4 acc[4][4];
#pragma unroll
  for (int fo = 0; fo < 4; ++fo)
#pragma unroll
    for (int fn = 0; fn < 4; ++fn) acc[fo][fn] = (f32x4){0.f, 0.f, 0.f, 0.f};

  const int obase = wv * 64;
#pragma unroll
  for (int ks = 0; ks < 8; ++ks) {
    f16x8 aw[4], bx[4];
#pragma unroll
    for (int fo = 0; fo < 4; ++fo)
      aw[fo] = *(const f16x8*)(W + (obase + fo * 16 + lr) * 256 + ks * 32 + lg * 8);
#pragma unroll
    for (int fn = 0; fn < 4; ++fn)
      bx[fn] = *(const f16x8*)&Xt[lr + 16 * fn][ks * 32 + lg * 8];
#pragma unroll
    for (int fo = 0; fo < 4; ++fo)
#pragma unroll
      for (int fn = 0; fn < 4; ++fn)
        acc[fo][fn] = __builtin_amdgcn_mfma_f32_16x16x32_f16(aw[fo], bx[fn], acc[fo][fn], 0, 0, 0);
  }

  // epilogue: C layout col n = lane&15, row o = 4*(lane>>4)+reg
#pragma unroll
  for (int fo = 0; fo < 4; ++fo) {
    const int orow = obase + fo * 16 + lg * 4;
    float bz[4];
#pragma unroll
    for (int r = 0; r < 4; ++r) bz[r] = bias[orow + r];
#pragma unroll
    for (int fn = 0; fn < 4; ++fn)
#pragma unroll
      for (int r = 0; r < 4; ++r)
        outp[(size_t)(orow + r) * HW + n0 + 16 * fn + lr] = (f16)(acc[fo][fn][r] + bz[r]);
  }
}

// ---------------------------------------------------------------------------
// Stage 2: per-(b,c) attention, two-phase, 512 threads (8 waves, 2/SIMD).
// No cross-phase register state: normalized P is stored in LDS (Pf plane).
// Phase 1: K in LDS (KA); single-pass QK^T; softmax; P*(1/sum) -> Pf (f16).
// Phase 2: V^T staged into KA; PV reads A-fragments straight from Pf.
// Tiles: 12 x 16 q-rows; wave w -> tile w, waves 0-3 also tile 8+w.
// LDS = 2 x 192x200 f16 = 153.6 KB -> 1 block/CU.
// ---------------------------------------------------------------------------
__global__ __launch_bounds__(512) void attn_kernel(
    const f16* __restrict__ qkv, float* __restrict__ outb) {
  const int c   = blockIdx.x;
  const int tid = threadIdx.x;
  const int l   = tid & 63;
  const int wv  = tid >> 6;          // 0..7
  const int lr  = l & 15, lg = l >> 4;

  const f16* __restrict__ q = qkv + (size_t)c * HW;
  const f16* __restrict__ k = qkv + (size_t)TS + (size_t)c * HW;
  const f16* __restrict__ v = qkv + 2 * (size_t)TS + (size_t)c * HW;
  float* __restrict__ outc = outb + (size_t)c * HW;

  __shared__ f16 KA[192][200];   // phase1: K [g][w]   phase2: V^T [w][g]
  __shared__ f16 Pf[192][200];   // normalized P [h][g]

  // ---- phase 1 staging: K -> KA (16B chunks, coalesced)
#pragma unroll
  for (int jj = 0; jj < 9; ++jj) {
    int id = tid + jj * 512;  // 4608 chunks
    int g = id / 24, wo = id % 24;
    *(f16x8*)&KA[g][wo * 8] = *(const f16x8*)(k + g * 192 + wo * 8);
  }
  __syncthreads();

#pragma unroll
  for (int rr = 0; rr < 2; ++rr) {
    if (rr == 0 || wv < 4) {
      const int h0 = (rr * 8 + wv) * 16;

      f16x8 aq[6];
#pragma unroll
      for (int ks = 0; ks < 6; ++ks)
        aq[ks] = *(const f16x8*)(q + (h0 + lr) * 192 + ks * 32 + lg * 8);

      f32x4 S[12];
#pragma unroll
      for (int fg = 0; fg < 12; ++fg) S[fg] = (f32x4){0.f, 0.f, 0.f, 0.f};
#pragma unroll
      for (int ks = 0; ks < 6; ++ks)
#pragma unroll
        for (int fg = 0; fg < 12; ++fg) {
          f16x8 bk_ = *(const f16x8*)&KA[16 * fg + lr][ks * 32 + lg * 8];
          S[fg] = __builtin_amdgcn_mfma_f32_16x16x32_f16(aq[ks], bk_, S[fg], 0, 0, 0);
        }

      // exact softmax per row (row = 4*lg + r; 16 lanes lr hold g-chunks),
      // normalize, store to Pf in [h][g] layout (C-layout-native scatter).
#pragma unroll
      for (int r = 0; r < 4; ++r) {
        float m = S[0][r];
#pragma unroll
        for (int fg = 1; fg < 12; ++fg) m = fmaxf(m, S[fg][r]);
        m = fmaxf(m, __shfl_xor(m, 1));
        m = fmaxf(m, __shfl_xor(m, 2));
        m = fmaxf(m, __shfl_xor(m, 4));
        m = fmaxf(m, __shfl_xor(m, 8));
        float s = 0.f;
#pragma unroll
        for (int fg = 0; fg < 12; ++fg) {
          float e = __expf(S[fg][r] - m);
          S[fg][r] = e;
          s += e;
        }
        s += __shfl_xor(s, 1);
        s += __shfl_xor(s, 2);
        s += __shfl_xor(s, 4);
        s += __shfl_xor(s, 8);
        float rs = 1.f / s;
#pragma unroll
        for (int fg = 0; fg < 12; ++fg)
          Pf[h0 + lg * 4 + r][16 * fg + lr] = (f16)(S[fg][r] * rs);
      }
    }
  }

  // ---- phase 2: stage V^T into KA (overwrites K)
  __syncthreads();
#pragma unroll
  for (int jj = 0; jj < 3; ++jj) {
    int id = tid + jj * 512;
    if (id < 1152) {
      int g0 = (id % 24) * 8, w0 = (id / 24) * 4;
      uint2 raw[8];
#pragma unroll
      for (int j = 0; j < 8; ++j) raw[j] = *(const uint2*)(v + (g0 + j) * 192 + w0);
#pragma unroll
      for (int qd = 0; qd < 4; ++qd) {
        union { unsigned short s[8]; f16x8 vec; } u;
#pragma unroll
        for (int j = 0; j < 8; ++j) u.s[j] = ((const unsigned short*)&raw[j])[qd];
        *(f16x8*)&KA[w0 + qd][g0] = u.vec;
      }
    }
  }
  __syncthreads();

#pragma unroll
  for (int rr = 0; rr < 2; ++rr) {
    if (rr == 0 || wv < 4) {
      const int h0 = (rr * 8 + wv) * 16;
      f32x4 O[12];
#pragma unroll
      for (int fn = 0; fn < 12; ++fn) O[fn] = (f32x4){0.f, 0.f, 0.f, 0.f};

#pragma unroll
      for (int ks = 0; ks < 6; ++ks) {
        f16x8 pa = *(const f16x8*)&Pf[h0 + lr][ks * 32 + lg * 8];  // A: row h, k = g
#pragma unroll
        for (int fn = 0; fn < 12; ++fn) {
          f16x8 bv_ = *(const f16x8*)&KA[16 * fn + lr][ks * 32 + lg * 8];  // B: col w, k = g
          O[fn] = __builtin_amdgcn_mfma_f32_16x16x32_f16(pa, bv_, O[fn], 0, 0, 0);
        }
      }

#pragma unroll
      for (int fn = 0; fn < 12; ++fn)
#pragma unroll
        for (int r = 0; r < 4; ++r)
          outc[(size_t)(h0 + lg * 4 + r) * 192 + 16 * fn + lr] = O[fn][r];
    }
  }
}

// ---------------------------------------------------------------------------
extern "C" void kernel_launch(void* const* d_in, const int* in_sizes, int n_in,
                              void* d_out, int out_size, void* d_ws, size_t ws_size,
                              hipStream_t stream) {
  const float* query = (const float*)d_in[0];
  const float* key_  = (const float*)d_in[1];
  const float* value = (const float*)d_in[2];
  const float* Wq    = (const float*)d_in[3];
  const float* bq    = (const float*)d_in[4];
  const float* Wk    = (const float*)d_in[5];
  const float* bk    = (const float*)d_in[6];
  const float* Wv    = (const float*)d_in[7];
  const float* bv    = (const float*)d_in[8];
  float* out = (float*)d_out;

  f16* wp  = (f16*)d_ws;                        // 3*65536 fp16 = 384 KB
  f16* qkv = (f16*)((char*)d_ws + 524288);      // 3*TS fp16 = 56.6 MB (per-batch, reused)

  convert_w_kernel<<<256, 256, 0, stream>>>(Wq, Wk, Wv, wp);

  for (int b = 0; b < 8; ++b) {
    const size_t off = (size_t)b * TS;
    conv1x1_kernel<<<dim3(576, 3), 256, 0, stream>>>(
        query + off, key_ + off, value + off, wp, bq, bk, bv, qkv);
    attn_kernel<<<256, 512, 0, stream>>>(qkv, out + off);
  }
}

// Round 7
// 706.837 us; speedup vs baseline: 2.7928x; 1.0095x over previous
//
#include <hip/hip_runtime.h>
#include <hip/hip_bf16.h>

typedef _Float16 f16;
typedef f16   f16x8 __attribute__((ext_vector_type(8)));
typedef float f32x4 __attribute__((ext_vector_type(4)));

#define HW 36864      /* 192*192 */
#define TS 9437184    /* 256*36864 : per-plane per-batch elements */

// ---------------------------------------------------------------------------
// Pre-kernel: W (fp32 256x256) -> 3 fp16 planes: Wq, Wk, Wv
// ---------------------------------------------------------------------------
__global__ __launch_bounds__(256) void convert_w_kernel(
    const float* __restrict__ wq, const float* __restrict__ wk,
    const float* __restrict__ wv, f16* __restrict__ wp) {
  int i = blockIdx.x * 256 + threadIdx.x;  // 0 .. 65535
  wp[i]             = (f16)wq[i];
  wp[65536 + i]     = (f16)wk[i];
  wp[2 * 65536 + i] = (f16)wv[i];
}

// ---------------------------------------------------------------------------
// Stage 1: 1x1 conv GEMM  out[o,n] = sum_i W[o,i] x[i,n] + b[o]
// Single-pass fp16 (fp32 accumulate). grid = (576, 3), block = 256.
// ---------------------------------------------------------------------------
__global__ __launch_bounds__(256) void conv1x1_kernel(
    const float* __restrict__ xq, const float* __restrict__ xk, const float* __restrict__ xv,
    const f16* __restrict__ wp,
    const float* __restrict__ bq, const float* __restrict__ bk, const float* __restrict__ bv,
    f16* __restrict__ qkv) {
  const int t = blockIdx.y;
  const float* __restrict__ in   = (t == 0) ? xq : (t == 1 ? xk : xv);
  const float* __restrict__ bias = (t == 0) ? bq : (t == 1 ? bk : bv);
  const f16* __restrict__ W = wp + t * 65536;
  f16* __restrict__ outp    = qkv + (size_t)t * TS;

  const int n0  = blockIdx.x * 64;
  const int tid = threadIdx.x;
  const int l   = tid & 63;
  const int wv  = tid >> 6;
  const int lr  = l & 15, lg = l >> 4;

  __shared__ f16 Xt[64][264];   // [n][i], +8 pad

#pragma unroll
  for (int it = 0; it < 8; ++it) {
    const int ib = it * 32 + wv * 8;
    float v[8];
#pragma unroll
    for (int j = 0; j < 8; ++j) v[j] = in[(size_t)(ib + j) * HW + n0 + l];
    union { f16 h[8]; f16x8 vec; } u;
#pragma unroll
    for (int j = 0; j < 8; ++j) u.h[j] = (f16)v[j];
    *(f16x8*)&Xt[l][ib] = u.vec;
  }
  __syncthreads();

  f32x4 acc[4][4];
#pragma unroll
  for (int fo = 0; fo < 4; ++fo)
#pragma unroll
    for (int fn = 0; fn < 4; ++fn) acc[fo][fn] = (f32x4){0.f, 0.f, 0.f, 0.f};

  const int obase = wv * 64;
#pragma unroll
  for (int ks = 0; ks < 8; ++ks) {
    f16x8 aw[4], bx[4];
#pragma unroll
    for (int fo = 0; fo < 4; ++fo)
      aw[fo] = *(const f16x8*)(W + (obase + fo * 16 + lr) * 256 + ks * 32 + lg * 8);
#pragma unroll
    for (int fn = 0; fn < 4; ++fn)
      bx[fn] = *(const f16x8*)&Xt[lr + 16 * fn][ks * 32 + lg * 8];
#pragma unroll
    for (int fo = 0; fo < 4; ++fo)
#pragma unroll
      for (int fn = 0; fn < 4; ++fn)
        acc[fo][fn] = __builtin_amdgcn_mfma_f32_16x16x32_f16(aw[fo], bx[fn], acc[fo][fn], 0, 0, 0);
  }

  // epilogue: C layout col n = lane&15, row o = 4*(lane>>4)+reg
#pragma unroll
  for (int fo = 0; fo < 4; ++fo) {
    const int orow = obase + fo * 16 + lg * 4;
    float bz[4];
#pragma unroll
    for (int r = 0; r < 4; ++r) bz[r] = bias[orow + r];
#pragma unroll
    for (int fn = 0; fn < 4; ++fn)
#pragma unroll
      for (int r = 0; r < 4; ++r)
        outp[(size_t)(orow + r) * HW + n0 + 16 * fn + lr] = (f16)(acc[fo][fn][r] + bz[r]);
  }
}

// ---------------------------------------------------------------------------
// Stage 2: per-(b,c) attention, two-phase, 768 threads (12 waves, 3/SIMD).
// Exactly ONE 16-row q-tile per wave -> perfect balance (R6 had 12 tiles on
// 8 waves: 25% idle). No cross-phase register state (P lives in LDS plane).
// Phase 1: K in LDS (KA); QK^T; softmax; normalized P -> Pf (f16).
// Phase 2: V^T staged into KA; PV reads A-fragments straight from Pf.
// LDS = 2 x 192x200 f16 = 153.6 KB -> 1 block/CU, all 12 waves resident.
// ---------------------------------------------------------------------------
__global__ __launch_bounds__(768) void attn_kernel(
    const f16* __restrict__ qkv, float* __restrict__ outb) {
  const int c   = blockIdx.x;
  const int tid = threadIdx.x;
  const int l   = tid & 63;
  const int wv  = tid >> 6;          // 0..11  == q-tile index
  const int lr  = l & 15, lg = l >> 4;

  const f16* __restrict__ q = qkv + (size_t)c * HW;
  const f16* __restrict__ k = qkv + (size_t)TS + (size_t)c * HW;
  const f16* __restrict__ v = qkv + 2 * (size_t)TS + (size_t)c * HW;
  float* __restrict__ outc = outb + (size_t)c * HW;

  __shared__ f16 KA[192][200];   // phase1: K [g][w]   phase2: V^T [w][g]
  __shared__ f16 Pf[192][200];   // normalized P [h][g]

  // ---- phase 1 staging: K -> KA (16B chunks, coalesced; 4608 = 768*6)
#pragma unroll
  for (int jj = 0; jj < 6; ++jj) {
    int id = tid + jj * 768;
    int g = id / 24, wo = id % 24;
    *(f16x8*)&KA[g][wo * 8] = *(const f16x8*)(k + g * 192 + wo * 8);
  }
  __syncthreads();

  {
    const int h0 = wv * 16;

    f16x8 aq[6];
#pragma unroll
    for (int ks = 0; ks < 6; ++ks)
      aq[ks] = *(const f16x8*)(q + (h0 + lr) * 192 + ks * 32 + lg * 8);

    f32x4 S[12];
#pragma unroll
    for (int fg = 0; fg < 12; ++fg) S[fg] = (f32x4){0.f, 0.f, 0.f, 0.f};
#pragma unroll
    for (int ks = 0; ks < 6; ++ks)
#pragma unroll
      for (int fg = 0; fg < 12; ++fg) {
        f16x8 bk_ = *(const f16x8*)&KA[16 * fg + lr][ks * 32 + lg * 8];
        S[fg] = __builtin_amdgcn_mfma_f32_16x16x32_f16(aq[ks], bk_, S[fg], 0, 0, 0);
      }

    // exact softmax per row (row = 4*lg + r; 16 lanes lr hold g-chunks),
    // normalize, store to Pf in [h][g] layout (C-layout-native scatter).
#pragma unroll
    for (int r = 0; r < 4; ++r) {
      float m = S[0][r];
#pragma unroll
      for (int fg = 1; fg < 12; ++fg) m = fmaxf(m, S[fg][r]);
      m = fmaxf(m, __shfl_xor(m, 1));
      m = fmaxf(m, __shfl_xor(m, 2));
      m = fmaxf(m, __shfl_xor(m, 4));
      m = fmaxf(m, __shfl_xor(m, 8));
      float s = 0.f;
#pragma unroll
      for (int fg = 0; fg < 12; ++fg) {
        float e = __expf(S[fg][r] - m);
        S[fg][r] = e;
        s += e;
      }
      s += __shfl_xor(s, 1);
      s += __shfl_xor(s, 2);
      s += __shfl_xor(s, 4);
      s += __shfl_xor(s, 8);
      float rs = 1.f / s;
#pragma unroll
      for (int fg = 0; fg < 12; ++fg)
        Pf[h0 + lg * 4 + r][16 * fg + lr] = (f16)(S[fg][r] * rs);
    }
  }

  // ---- phase 2: stage V^T into KA (overwrites K); 1152 jobs over 768 thr
  __syncthreads();
#pragma unroll
  for (int jj = 0; jj < 2; ++jj) {
    int id = tid + jj * 768;
    if (id < 1152) {
      int g0 = (id % 24) * 8, w0 = (id / 24) * 4;
      uint2 raw[8];
#pragma unroll
      for (int j = 0; j < 8; ++j) raw[j] = *(const uint2*)(v + (g0 + j) * 192 + w0);
#pragma unroll
      for (int qd = 0; qd < 4; ++qd) {
        union { unsigned short s[8]; f16x8 vec; } u;
#pragma unroll
        for (int j = 0; j < 8; ++j) u.s[j] = ((const unsigned short*)&raw[j])[qd];
        *(f16x8*)&KA[w0 + qd][g0] = u.vec;
      }
    }
  }
  __syncthreads();

  {
    const int h0 = wv * 16;
    f32x4 O[12];
#pragma unroll
    for (int fn = 0; fn < 12; ++fn) O[fn] = (f32x4){0.f, 0.f, 0.f, 0.f};

#pragma unroll
    for (int ks = 0; ks < 6; ++ks) {
      f16x8 pa = *(const f16x8*)&Pf[h0 + lr][ks * 32 + lg * 8];  // A: row h, k = g
#pragma unroll
      for (int fn = 0; fn < 12; ++fn) {
        f16x8 bv_ = *(const f16x8*)&KA[16 * fn + lr][ks * 32 + lg * 8];  // B: col w, k = g
        O[fn] = __builtin_amdgcn_mfma_f32_16x16x32_f16(pa, bv_, O[fn], 0, 0, 0);
      }
    }

#pragma unroll
    for (int fn = 0; fn < 12; ++fn)
#pragma unroll
      for (int r = 0; r < 4; ++r)
        outc[(size_t)(h0 + lg * 4 + r) * 192 + 16 * fn + lr] = O[fn][r];
  }
}

// ---------------------------------------------------------------------------
extern "C" void kernel_launch(void* const* d_in, const int* in_sizes, int n_in,
                              void* d_out, int out_size, void* d_ws, size_t ws_size,
                              hipStream_t stream) {
  const float* query = (const float*)d_in[0];
  const float* key_  = (const float*)d_in[1];
  const float* value = (const float*)d_in[2];
  const float* Wq    = (const float*)d_in[3];
  const float* bq    = (const float*)d_in[4];
  const float* Wk    = (const float*)d_in[5];
  const float* bk    = (const float*)d_in[6];
  const float* Wv    = (const float*)d_in[7];
  const float* bv    = (const float*)d_in[8];
  float* out = (float*)d_out;

  f16* wp  = (f16*)d_ws;                        // 3*65536 fp16 = 384 KB
  f16* qkv = (f16*)((char*)d_ws + 524288);      // 3*TS fp16 = 56.6 MB (per-batch, reused)

  convert_w_kernel<<<256, 256, 0, stream>>>(Wq, Wk, Wv, wp);

  for (int b = 0; b < 8; ++b) {
    const size_t off = (size_t)b * TS;
    conv1x1_kernel<<<dim3(576, 3), 256, 0, stream>>>(
        query + off, key_ + off, value + off, wp, bq, bk, bv, qkv);
    attn_kernel<<<256, 768, 0, stream>>>(qkv, out + off);
  }
}